// Round 6
// baseline (167.286 us; speedup 1.0000x reference)
//
#include <hip/hip_runtime.h>

// CrossProductLayer: out[b, f] = t(b, f) * w[f]
//   f in [0,128)    : x[b,f]^2
//   f in [128,256)  : x[b,f-128]
//   f in [256,8384) : x[b,i]*x[b,j]*0.5, (i,j) = triu_indices(128, k=1)[f-256]
// B=16384, F=8384. 549 MB fp32 output -> HBM-write-bound.
//
// R6: NO LDS, NO BARRIER. All structural variants with an LDS staging phase
// converge at 101-121 us vs the 83 us fill-rate floor; hypothesis: the
// load->barrier->store phase structure (and LDS on the store dependency
// chain) costs ~18 us across 8 block-residency waves. x is only 8 MB and a
// block's 64-row tile is 32 KB -> read x[r][i], x[r][j] straight from L1/L2
// (j lane-stride-1 -> coalesced; i near-broadcast). Keep the empirically
// best store pattern: one dword store per lane (R2 beat all wider-store
// variants). Decode once per thread, amortized over 64 rows.
// fp-exact: *1.0 exact; (xi*xj)*(0.5*w) == ((xi*xj)*0.5)*w (absmax 0.0 R3-R5).

constexpr int BATCH = 16384;
constexpr int NIN   = 128;
constexpr int NFEAT = 2 * NIN + NIN * (NIN - 1) / 2;  // 8384
constexpr int TPB   = 256;
constexpr int BROWS = 64;  // rows per block (decode amortization)

__device__ __forceinline__ int pair_off(int i) { return i * (NIN - 1) - (i * (i - 1)) / 2; }

__global__ __launch_bounds__(TPB) void cpl_kernel(const float* __restrict__ x,
                                                  const float* __restrict__ w,
                                                  float* __restrict__ out) {
    const int tid = threadIdx.x;
    const int f   = blockIdx.x * TPB + tid;
    if (f >= NFEAT) return;
    const int r0 = blockIdx.y * BROWS;

    // Decode this thread's feature once (branches wave-uniform: boundaries
    // 128/256 align to wave granularity 64).
    int  i1, i2;
    bool single = false;
    float ws;
    if (f < NIN) {                 // squares: x*x*w
        i1 = f; i2 = f; ws = w[f];
    } else if (f < 2 * NIN) {      // singles: x*w
        i1 = f - NIN; i2 = i1; ws = w[f]; single = true;
    } else {                       // pairs: xi*xj*(0.5*w)
        const int p = f - 2 * NIN;
        float s = sqrtf((float)(65025 - 8 * p));
        int   i = (int)((255.0f - s) * 0.5f);
        i = min(max(i, 0), NIN - 2);
        while (pair_off(i + 1) <= p) ++i;   // exact integer fix-up
        while (pair_off(i)     >  p) --i;
        i1 = i;
        i2 = i + 1 + (p - pair_off(i));
        ws = w[f] * 0.5f;                   // exact scaling
    }

    const float* xp = x + (size_t)r0 * NIN;
    float*       op = out + (size_t)r0 * NFEAT + f;
#pragma unroll
    for (int r = 0; r < BROWS; ++r) {
        float xi = xp[(size_t)r * NIN + i1];  // L1/L2-resident, near-broadcast
        float xj = xp[(size_t)r * NIN + i2];  // lane-stride-1, coalesced
        if (single) xj = 1.0f;                // wave-uniform select
        op[(size_t)r * NFEAT] = xi * xj * ws; // fire-and-forget dword store
    }
}

extern "C" void kernel_launch(void* const* d_in, const int* in_sizes, int n_in,
                              void* d_out, int out_size, void* d_ws, size_t ws_size,
                              hipStream_t stream) {
    const float* x = (const float*)d_in[0];  // [16384, 128]
    const float* w = (const float*)d_in[1];  // [8384]
    float*     out = (float*)d_out;          // [16384, 8384]

    dim3 grid((NFEAT + TPB - 1) / TPB,  // 33 feature windows
              BATCH / BROWS);           // 256 row groups
    cpl_kernel<<<grid, TPB, 0, stream>>>(x, w, out);
}

// Round 7
// 112.476 us; speedup vs baseline: 1.4873x; 1.4873x over previous
//
#include <hip/hip_runtime.h>

// CrossProductLayer: out[b, f] = t(b, f) * w[f]
//   f in [0,128)    : x[b,f]^2
//   f in [128,256)  : x[b,f-128]
//   f in [256,8384) : x[b,i]*x[b,j]*0.5, (i,j) = triu_indices(128, k=1)[f-256]
// B=16384, F=8384. 549 MB fp32 output -> HBM-write-bound.
//
// R7 = R2 (champion: 1 feat/thread, 32-row LDS tile, dword stores) + two
// traffic fixes that leave the inner loop untouched:
//  1. XCD-coherent mapping: linear grid, row_group = wid % 512, f_win = wid/512.
//     512 % 8 == 0 -> all 33 f-window blocks of a row-group have the same
//     (id mod 8) -> same XCD -> x-tile fetched from HBM once, not 8x.
//  2. Non-temporal stores: 549 MB streaming output doesn't retain dirty lines
//     in the 4 MB/XCD L2, keeping the x tiles + w resident.
// fp-exact: (xi*xj)*(0.5*w) == ((xi*xj)*0.5)*w; *1.0 exact (absmax 0.0 R2-R6).

constexpr int BATCH  = 16384;
constexpr int NIN    = 128;
constexpr int NFEAT  = 2 * NIN + NIN * (NIN - 1) / 2;  // 8384
constexpr int TPB    = 256;
constexpr int BROWS  = 32;
constexpr int NGROUP = BATCH / BROWS;                   // 512 row-groups
constexpr int NFWIN  = (NFEAT + TPB - 1) / TPB;         // 33 feature windows

__device__ __forceinline__ int pair_off(int i) { return i * (NIN - 1) - (i * (i - 1)) / 2; }

__global__ __launch_bounds__(TPB) void cpl_kernel(const float* __restrict__ x,
                                                  const float* __restrict__ w,
                                                  float* __restrict__ out) {
    __shared__ float xs[BROWS * NIN];

    const int tid = threadIdx.x;
    const int wid = blockIdx.x;
    const int r0  = (wid % NGROUP) * BROWS;  // row-group fastest: same XCD shares tile
    const int fw  = wid / NGROUP;            // feature window

    // Cooperative tile load: 32 rows x 128 floats = 1024 float4, 4 per thread.
    {
        const float4* src = reinterpret_cast<const float4*>(x + (size_t)r0 * NIN);
        float4*       dst = reinterpret_cast<float4*>(xs);
#pragma unroll
        for (int k = 0; k < (BROWS * NIN / 4) / TPB; ++k)
            dst[k * TPB + tid] = src[k * TPB + tid];
    }
    __syncthreads();

    const int f = fw * TPB + tid;
    if (f >= NFEAT) return;

    // Decode this thread's feature once; amortized over BROWS rows.
    // Branches wave-uniform: boundaries 128/256 are multiples of 64.
    int i1, i2, mode;  // 0=square, 1=single, 2=pair
    if (f < NIN) {
        i1 = f; i2 = f; mode = 0;
    } else if (f < 2 * NIN) {
        i1 = f - NIN; i2 = f - NIN; mode = 1;
    } else {
        const int p = f - 2 * NIN;
        float s = sqrtf((float)(65025 - 8 * p));  // invert off(i) <= p
        int   i = (int)((255.0f - s) * 0.5f);
        i = min(max(i, 0), NIN - 2);
        while (pair_off(i + 1) <= p) ++i;  // exact integer fix-up
        while (pair_off(i)     >  p) --i;
        i1 = i;
        i2 = i + 1 + (p - pair_off(i));
        mode = 2;
    }
    const float wf = w[f];

    float* op = out + (size_t)r0 * NFEAT + f;
#pragma unroll
    for (int b = 0; b < BROWS; ++b) {
        const float xi = xs[b * NIN + i1];
        const float xj = xs[b * NIN + i2];  // lane-stride-1: conflict-free
        float p = xi * xj;                  // squares & pairs
        if (mode == 1) p = xi;              // singles
        if (mode == 2) p *= 0.5f;           // pairs (same fp order as ref)
        __builtin_nontemporal_store(p * wf, op + (size_t)b * NFEAT);
    }
}

extern "C" void kernel_launch(void* const* d_in, const int* in_sizes, int n_in,
                              void* d_out, int out_size, void* d_ws, size_t ws_size,
                              hipStream_t stream) {
    const float* x = (const float*)d_in[0];  // [16384, 128]
    const float* w = (const float*)d_in[1];  // [8384]
    float*     out = (float*)d_out;          // [16384, 8384]

    cpl_kernel<<<dim3(NFWIN * NGROUP), dim3(TPB), 0, stream>>>(x, w, out);
}